// Round 9
// baseline (325.318 us; speedup 1.0000x reference)
//
#include <hip/hip_runtime.h>
#include <hip/hip_bf16.h>
#include <stdint.h>

typedef __bf16 bf16x8 __attribute__((ext_vector_type(8)));
typedef float f32x4 __attribute__((ext_vector_type(4)));

__device__ __forceinline__ unsigned short f2bf(float f) {
  union { float f; unsigned int u; } v; v.f = f;
  unsigned int u = v.u;
  unsigned int r = (u + 0x7fffu + ((u >> 16) & 1u)) >> 16;
  return (unsigned short)r;
}
__device__ __forceinline__ float bf2f(unsigned short s) {
  union { unsigned int u; float f; } v; v.u = ((unsigned int)s) << 16; return v.f;
}

// ---------------- elementwise fp32 -> bf16 (x) ----------------
__global__ __launch_bounds__(256) void conv_f2bf(const float* __restrict__ in,
                                                 unsigned short* __restrict__ out, int n4) {
  int i = blockIdx.x * 256 + threadIdx.x;
  if (i < n4) {
    float4 v = ((const float4*)in)[i];
    ushort4 o;
    o.x = f2bf(v.x); o.y = f2bf(v.y); o.z = f2bf(v.z); o.w = f2bf(v.w);
    ((ushort4*)out)[i] = o;
  }
}

// ---------------- per-qgroup(16) live-tile bitmaps ----------------
__global__ __launch_bounds__(256) void prep_bitmap(const int* __restrict__ seq,
                                                   const int* __restrict__ fr,
                                                   const int* __restrict__ nz,
                                                   const int* __restrict__ wsz,
                                                   unsigned long long* __restrict__ tbm,
                                                   int S) {
  __shared__ int ks_[3072];
  __shared__ unsigned int tm_[96];
  int tid = threadIdx.x, W = wsz[0];
  for (int i = tid; i < S; i += 256) {
    int sq = seq[i];
    ks_[i] = (sq < 0) ? 0 : ((1 << 9) | ((nz[i] & 1) << 8) | (fr[i] & 15) | (sq << 10));
  }
  __syncthreads();
  for (int t = tid; t < S / 32; t += 256) {
    unsigned int m = 0;
    for (int j = 0; j < 32; j++) {
      int a = ks_[t * 32 + j];
      if (a & (1 << 9)) m |= (a & (1 << 8)) ? (1u << (16 + (a & 15))) : (1u << (a & 15));
    }
    tm_[t] = m;
  }
  __syncthreads();
  for (int qg = tid; qg < S / 16; qg += 256) {
    unsigned int allowed = 0;
    for (int j = 0; j < 16; j++) {
      int a = ks_[qg * 16 + j];
      if (!(a & (1 << 9))) continue;
      int fq = a & 15, nq = (a >> 8) & 1;
      int lo = fq - W; if (lo < 0) lo = 0;
      unsigned int lom = ~((1u << lo) - 1);
      if (nq) allowed |= (((1u << (fq + 1)) - 1) & lom) << 16;
      else    allowed |= ((((1u << fq) - 1) & lom) << 16) | (1u << fq);
    }
    unsigned long long b0 = 0, b1 = 0;
    for (int t = 0; t < 96; t++)
      if (tm_[t] & allowed) { if (t < 64) b0 |= 1ull << t; else b1 |= 1ull << (t - 64); }
    tbm[qg * 2] = b0; tbm[qg * 2 + 1] = b1;
  }
}

// ---------------- mask bits: mb[qg][tile][lane], bit (nt*4+r) ----------------
__global__ __launch_bounds__(256) void prep_mask(const int* __restrict__ seq,
                                                 const int* __restrict__ fr,
                                                 const int* __restrict__ nz,
                                                 const int* __restrict__ wsz,
                                                 unsigned char* __restrict__ mb, int S) {
  int qg = blockIdx.y, t0 = blockIdx.x * 4;
  __shared__ int qs[16], qf_[16], qn[16], ksq[128], kfr[128], knz[128];
  int tid = threadIdx.x;
  if (tid < 16) {
    int q = qg * 16 + tid; qs[tid] = seq[q]; qf_[tid] = fr[q]; qn[tid] = nz[q];
  } else if (tid < 144) {
    int i = tid - 16; int k = t0 * 32 + i;
    ksq[i] = seq[k]; kfr[i] = fr[k]; knz[i] = nz[k];
  }
  __syncthreads();
  int wave = tid >> 6, lane = tid & 63, quad = lane >> 4, l16 = lane & 15;
  int W = wsz[0];
  unsigned int byte = 0;
  for (int nt = 0; nt < 2; nt++)
    for (int r = 0; r < 4; r++) {
      int qi = quad * 4 + r;
      int ki = wave * 32 + nt * 16 + l16;
      bool ok  = (qs[qi] == ksq[ki]) && (qs[qi] >= 0) && (ksq[ki] >= 0);
      bool c2c = (qn[qi] == 1) && (knz[ki] == 1) && (kfr[ki] <= qf_[qi]);
      bool n2c = (qn[qi] == 0) && (knz[ki] == 1) && (kfr[ki] <  qf_[qi]);
      bool n2n = (qn[qi] == 0) && (knz[ki] == 0) && (kfr[ki] == qf_[qi]);
      int df = qf_[qi] - kfr[ki]; df = df < 0 ? -df : df;
      if ((c2c || n2c || n2n) && ok && (df <= W)) byte |= 1u << (nt * 4 + r);
    }
  mb[((size_t)qg * 96 + t0 + wave) * 64 + lane] = (unsigned char)byte;
}

// ---------------- Wq/Wk/Wv/Wo [K][N] fp32 -> Wt [4*1536][K] bf16 ----------------
__global__ __launch_bounds__(256) void conv_wt4(const float* __restrict__ W0,
                                                const float* __restrict__ W1,
                                                const float* __restrict__ W2,
                                                const float* __restrict__ W3,
                                                unsigned short* __restrict__ Wt) {
  const int K = 1536, N = 1536;
  const float* W = blockIdx.z == 0 ? W0 : (blockIdx.z == 1 ? W1 : (blockIdx.z == 2 ? W2 : W3));
  __shared__ __align__(16) unsigned short t[64][65];
  int k0 = blockIdx.x * 64, n0 = blockIdx.y * 64;
  for (int i = 0; i < 16; i++) {
    int e = threadIdx.x + i * 256;
    int r = e >> 6, c = e & 63;
    t[r][c] = f2bf(W[(size_t)(k0 + r) * N + n0 + c]);
  }
  __syncthreads();
  for (int i = 0; i < 16; i++) {
    int e = threadIdx.x + i * 256;
    int r = e >> 6, c = e & 63;
    Wt[(size_t)(blockIdx.z * 1536 + n0 + r) * K + k0 + c] = t[c][r];
  }
}

// ---------------- fused QKV GEMM ----------
// region 0 -> qt bf16 [h][3072][128] (pre-norm) + ssq[0] atomics
// region 1 -> ktb bf16 [h][3072][128] (pre-norm) + ssq[1] atomics
// region 2 -> vtb bf16 tile-blocked [h][96 tile][128 d][32 s]
// Epilogue routes the 128x128 C tile through LDS (reusing As/Bs) for 16B stores.
__global__ __launch_bounds__(256) void gemm_qkv(
    const unsigned short* __restrict__ A, const unsigned short* __restrict__ Bt,
    const float* __restrict__ bq, const float* __restrict__ bk, const float* __restrict__ bv,
    unsigned short* __restrict__ qt, unsigned short* __restrict__ ktb,
    unsigned short* __restrict__ vtb, float* __restrict__ ssq, int S) {
  const int K = 1536;
  __shared__ __align__(16) unsigned short smem[16384];   // As | Bs, reused as Cs
  unsigned short* As = smem;
  unsigned short* Bs = smem + 8192;
  unsigned short* Cs = smem;
  int tid = threadIdx.x, wave = tid >> 6, lane = tid & 63;
  int quad = lane >> 4, l16 = lane & 15;
  int m0 = blockIdx.x * 128, n0 = blockIdx.y * 128;
  int wm = (wave & 1) * 64, wn = (wave >> 1) * 64;
  int lr = lane >> 3, lc = (lane & 7) * 8;
  f32x4 acc[4][4] = {};
  for (int k0 = 0; k0 < K; k0 += 64) {
    for (int c = 0; c < 4; c++) {
      int chunk = wave * 4 + c;
      int row = chunk * 8 + lr;
      const unsigned short* ga = &A[(size_t)(m0 + row) * K + k0 + lc];
      const unsigned short* gb = &Bt[(size_t)(n0 + row) * K + k0 + lc];
      __builtin_amdgcn_global_load_lds(
          (const __attribute__((address_space(1))) unsigned int*)ga,
          (__attribute__((address_space(3))) unsigned int*)(As + chunk * 512), 16, 0, 0);
      __builtin_amdgcn_global_load_lds(
          (const __attribute__((address_space(1))) unsigned int*)gb,
          (__attribute__((address_space(3))) unsigned int*)(Bs + chunk * 512), 16, 0, 0);
    }
    __syncthreads();
    for (int kk = 0; kk < 64; kk += 32) {
      bf16x8 af[4], bfr[4];
      for (int i = 0; i < 4; i++)
        af[i] = *(const bf16x8*)&As[(wm + i * 16 + l16) * 64 + kk + quad * 8];
      for (int j = 0; j < 4; j++)
        bfr[j] = *(const bf16x8*)&Bs[(wn + j * 16 + l16) * 64 + kk + quad * 8];
      for (int i = 0; i < 4; i++)
        for (int j = 0; j < 4; j++)
          acc[i][j] = __builtin_amdgcn_mfma_f32_16x16x32_bf16(af[i], bfr[j], acc[i][j], 0, 0, 0);
    }
    __syncthreads();   // also guarantees As/Bs safe to reuse as Cs after loop
  }
  int region = (n0 >= 3072) ? 2 : (n0 >= 1536 ? 1 : 0);
  int cbase = n0 - region * 1536;
  int hh = cbase >> 7;
  if (region < 2) {
    const float* bias = region == 0 ? bq : bk;
    float* ssqp = ssq + region * 3072;
    float ss[4][4] = {};
    for (int j = 0; j < 4; j++) {
      int col = cbase + wn + j * 16 + l16;
      float b = bias[col];
      int cp = wn + j * 16 + l16;
      for (int i = 0; i < 4; i++)
        for (int r = 0; r < 4; r++) {
          float v = acc[i][j][r] + b;
          ss[i][r] += v * v;
          int sp = wm + i * 16 + quad * 4 + r;
          Cs[sp * 128 + cp] = f2bf(v);
        }
    }
    for (int i = 0; i < 4; i++)
      for (int r = 0; r < 4; r++) {
        float v = ss[i][r];
        for (int o = 1; o < 16; o <<= 1) v += __shfl_xor(v, o);
        if (l16 == 0)
          atomicAdd(&ssqp[m0 + wm + i * 16 + quad * 4 + r], v);
      }
    __syncthreads();
    unsigned short* outp = (region == 0 ? qt : ktb) + (size_t)hh * 393216 + (size_t)m0 * 128;
    for (int p = 0; p < 8; p++) {
      int o = p * 2048 + tid * 8;
      *(uint4*)&outp[o] = *(const uint4*)&Cs[o];
    }
  } else {
    // V: transposed + XOR-swizzled LDS: Cs[cp*128 + (sp ^ (cp&15)*8)]
    for (int j = 0; j < 4; j++) {
      int d = cbase + wn + j * 16 + l16;
      float b = bv[d];
      int cp = wn + j * 16 + l16;
      int c8 = l16 * 8;          // (cp & 15) * 8
      for (int i = 0; i < 4; i++)
        for (int r = 0; r < 4; r++) {
          int sp = wm + i * 16 + quad * 4 + r;
          Cs[cp * 128 + (sp ^ c8)] = f2bf(acc[i][j][r] + b);
        }
    }
    __syncthreads();
    unsigned short* outp = vtb + ((size_t)hh * 96 + (m0 >> 5)) * 4096;
    for (int p = 0; p < 8; p++) {
      int o = p * 2048 + tid * 8;
      int tile = o >> 12, rem = o & 4095;
      int dd = rem >> 5, s31 = rem & 31;
      int laddr = dd * 128 + ((tile * 32 + s31) ^ ((dd & 15) * 8));
      *(uint4*)&outp[o] = *(const uint4*)&Cs[laddr];
    }
  }
}

// ---------------- in-place RMS rescale of [h][s][128] bf16 q/k ----------------
__global__ __launch_bounds__(192) void rms_scale(unsigned short* __restrict__ qt,
                                                 unsigned short* __restrict__ ktb,
                                                 const float* __restrict__ ssq,
                                                 const float* __restrict__ gq,
                                                 const float* __restrict__ gk) {
  int row = blockIdx.x, buf = blockIdx.y;
  unsigned short* p = buf ? ktb : qt;
  const float* g = buf ? gk : gq;
  float sc = rsqrtf(ssq[buf * 3072 + row] * (1.0f / 1536.0f) + 1e-5f);
  int c = threadIdx.x * 8;
  int hh = c >> 7, dd = c & 127;
  size_t idx = (size_t)hh * 393216 + (size_t)row * 128 + dd;
  ushort4 a = *(ushort4*)&p[idx];
  ushort4 b = *(ushort4*)&p[idx + 4];
  float4 g0 = *(const float4*)&g[c];
  float4 g1 = *(const float4*)&g[c + 4];
  a.x = f2bf(bf2f(a.x) * sc * g0.x); a.y = f2bf(bf2f(a.y) * sc * g0.y);
  a.z = f2bf(bf2f(a.z) * sc * g0.z); a.w = f2bf(bf2f(a.w) * sc * g0.w);
  b.x = f2bf(bf2f(b.x) * sc * g1.x); b.y = f2bf(bf2f(b.y) * sc * g1.y);
  b.z = f2bf(bf2f(b.z) * sc * g1.z); b.w = f2bf(bf2f(b.w) * sc * g1.w);
  *(ushort4*)&p[idx] = a;
  *(ushort4*)&p[idx + 4] = b;
}

// ---------------- GEMM 128x64 (Wo): fp32 out + bias ----------------
__global__ __launch_bounds__(256) void gemm_wo(
    const unsigned short* __restrict__ A, const unsigned short* __restrict__ Bt,
    const float* __restrict__ bias, float* __restrict__ C, int M, int N, int K) {
  __shared__ __align__(16) unsigned short As[128 * 64];
  __shared__ __align__(16) unsigned short Bs[64 * 64];
  int tid = threadIdx.x, wave = tid >> 6, lane = tid & 63;
  int quad = lane >> 4, l16 = lane & 15;
  int m0 = blockIdx.x * 128, n0 = blockIdx.y * 64;
  int wm = (wave & 1) * 64, wn = (wave >> 1) * 32;
  int lr = lane >> 3, lc = (lane & 7) * 8;
  f32x4 acc[4][2] = {};
  for (int k0 = 0; k0 < K; k0 += 64) {
    for (int c = 0; c < 4; c++) {
      int chunk = wave * 4 + c;
      int row = chunk * 8 + lr;
      const unsigned short* ga = &A[(size_t)(m0 + row) * K + k0 + lc];
      __builtin_amdgcn_global_load_lds(
          (const __attribute__((address_space(1))) unsigned int*)ga,
          (__attribute__((address_space(3))) unsigned int*)(As + chunk * 512), 16, 0, 0);
    }
    for (int c = 0; c < 2; c++) {
      int chunk = wave * 2 + c;
      int row = chunk * 8 + lr;
      const unsigned short* gb = &Bt[(size_t)(n0 + row) * K + k0 + lc];
      __builtin_amdgcn_global_load_lds(
          (const __attribute__((address_space(1))) unsigned int*)gb,
          (__attribute__((address_space(3))) unsigned int*)(Bs + chunk * 512), 16, 0, 0);
    }
    __syncthreads();
    for (int kk = 0; kk < 64; kk += 32) {
      bf16x8 af[4], bfr[2];
      for (int i = 0; i < 4; i++)
        af[i] = *(const bf16x8*)&As[(wm + i * 16 + l16) * 64 + kk + quad * 8];
      for (int j = 0; j < 2; j++)
        bfr[j] = *(const bf16x8*)&Bs[(wn + j * 16 + l16) * 64 + kk + quad * 8];
      for (int i = 0; i < 4; i++)
        for (int j = 0; j < 2; j++)
          acc[i][j] = __builtin_amdgcn_mfma_f32_16x16x32_bf16(af[i], bfr[j], acc[i][j], 0, 0, 0);
    }
    __syncthreads();
  }
  for (int j = 0; j < 2; j++) {
    int col = n0 + wn + j * 16 + l16;
    float b = bias[col];
    for (int i = 0; i < 4; i++)
      for (int r = 0; r < 4; r++)
        C[(size_t)(m0 + wm + i * 16 + quad * 4 + r) * N + col] = acc[i][j][r] + b;
  }
}

// ---------------- flash attention: block = 64q x head x split; no online max ----------
// p = exp(s*scale - 16); partials: o_split = (sum p v)/l_split stored bf16, l stored fp32.
__global__ __launch_bounds__(256) void attn(
    const unsigned short* __restrict__ qt,   // [12][3072][128]
    const unsigned short* __restrict__ kt,   // [12][3072][128] (tile view [12][96][32][128])
    const unsigned short* __restrict__ vt,   // [12][96][128][32]
    const unsigned char* __restrict__ mb,    // [192][96][64]
    const unsigned long long* __restrict__ tbm, // [192][2]
    unsigned short* __restrict__ op0b, unsigned short* __restrict__ op1b,
    float* __restrict__ lp, int S) {
  const int h = blockIdx.x;
  const int qb64 = blockIdx.y;
  const int split = blockIdx.z;
  int tid = threadIdx.x, wave = tid >> 6, lane = tid & 63;
  int quad = lane >> 4, l16 = lane & 15;
  const float scale = 0.088388347648318447f; // 1/sqrt(128)

  __shared__ __align__(16) unsigned short Ks[2][4096]; // [32 key][16 chunk, cc^=key&15]
  __shared__ __align__(16) unsigned short Vs[2][4096]; // [128 row][4 chunk, cc^=(row>>1)&3]
  __shared__ __align__(16) unsigned short pshare[4][16][40];

  int qg = qb64 * 4 + wave;
  unsigned long long bm0 = tbm[(qb64 * 4) * 2]     | tbm[(qb64 * 4 + 1) * 2] |
                           tbm[(qb64 * 4 + 2) * 2] | tbm[(qb64 * 4 + 3) * 2];
  unsigned long long bm1 = tbm[(qb64 * 4) * 2 + 1]     | tbm[(qb64 * 4 + 1) * 2 + 1] |
                           tbm[(qb64 * 4 + 2) * 2 + 1] | tbm[(qb64 * 4 + 3) * 2 + 1];
  unsigned long long wb0 = tbm[qg * 2], wb1 = tbm[qg * 2 + 1];

  const unsigned short* kth = kt + (size_t)h * 96 * 4096;
  const unsigned short* vth = vt + (size_t)h * 96 * 4096;
  const unsigned char* mbq = mb + (size_t)qg * 96 * 64;

  bf16x8 qf[4];
  {
    const unsigned short* qp = qt + ((size_t)(h * 192 + qg) * 16 + l16) * 128 + quad * 8;
    for (int ks = 0; ks < 4; ks++) qf[ks] = *(const bf16x8*)&qp[ks * 32];
  }

  f32x4 oacc[8] = {};
  f32x4 lacc = {};
  const __bf16 onebf = (__bf16)1.0f;
  const bf16x8 ones = {onebf, onebf, onebf, onebf, onebf, onebf, onebf, onebf};

#define POP(dst) do { \
    if (bm0) { dst = __builtin_ctzll(bm0); bm0 &= bm0 - 1; } \
    else if (bm1) { dst = 64 + __builtin_ctzll(bm1); bm1 &= bm1 - 1; } \
    else dst = -1; } while (0)

  // dest ushort offset for slot (j*256+tid): bytes = slot*16 -> ushorts = j*2048 + wave*512
#define STAGE(t_, b_) do { \
    for (int j = 0; j < 2; j++) { \
      int slot = j * 256 + tid; \
      int key = slot >> 4, cc = slot & 15; \
      const unsigned short* src = kth + (size_t)(t_) * 4096 + key * 128 + (cc ^ (key & 15)) * 8; \
      __builtin_amdgcn_global_load_lds( \
          (const __attribute__((address_space(1))) unsigned int*)src, \
          (__attribute__((address_space(3))) unsigned int*)(&Ks[b_][0] + j * 2048 + wave * 512), \
          16, 0, 0); \
    } \
    for (int j = 0; j < 2; j++) { \
      int slot = j * 256 + tid; \
      int row = slot >> 2, cc = slot & 3; \
      const unsigned short* src = vth + (size_t)(t_) * 4096 + row * 32 + (cc ^ ((row >> 1) & 3)) * 8; \
      __builtin_amdgcn_global_load_lds( \
          (const __attribute__((address_space(1))) unsigned int*)src, \
          (__attribute__((address_space(3))) unsigned int*)(&Vs[b_][0] + j * 2048 + wave * 512), \
          16, 0, 0); \
    } } while (0)

  int t, dsc;
  if (split) POP(dsc);
  POP(t);
  unsigned int mbyte = 0;
  if (t >= 0) { STAGE(t, 0); mbyte = mbq[t * 64 + lane]; }
  __syncthreads();
  int buf = 0;

  while (t >= 0) {
    POP(dsc);
    int tn; POP(tn);
    unsigned int mbyte2 = 0;
    if (tn >= 0) { STAGE(tn, buf ^ 1); mbyte2 = mbq[tn * 64 + lane]; }

    bool live = (t < 64) ? ((wb0 >> t) & 1) : ((wb1 >> (t - 64)) & 1);
    if (live) {
      f32x4 sacc[2] = {};
      for (int nt = 0; nt < 2; nt++) {
        int key = nt * 16 + l16;
        for (int ks = 0; ks < 4; ks++) {
          int cc = (ks * 4 + quad) ^ l16;
          bf16x8 kf = *(const bf16x8*)&Ks[buf][(key * 16 + cc) * 8];
          sacc[nt] = __builtin_amdgcn_mfma_f32_16x16x32_bf16(qf[ks], kf, sacc[nt], 0, 0, 0);
        }
      }
      // fixed-offset exp (no online max)
      for (int nt = 0; nt < 2; nt++)
        for (int r = 0; r < 4; r++) {
          float e = __expf(sacc[nt][r] * scale - 16.0f);
          float p = ((mbyte >> (nt * 4 + r)) & 1) ? e : 0.0f;
          pshare[wave][quad * 4 + r][nt * 16 + l16] = f2bf(p);
        }
      __asm__ __volatile__("s_waitcnt lgkmcnt(0)" ::: "memory");
      bf16x8 pf = *(const bf16x8*)&pshare[wave][l16][quad * 8];
      for (int d = 0; d < 8; d++) {
        int row = d * 16 + l16;
        int cc = quad ^ ((l16 >> 1) & 3);
        bf16x8 vf = *(const bf16x8*)&Vs[buf][(row * 4 + cc) * 8];
        oacc[d] = __builtin_amdgcn_mfma_f32_16x16x32_bf16(pf, vf, oacc[d], 0, 0, 0);
      }
      lacc = __builtin_amdgcn_mfma_f32_16x16x32_bf16(pf, ones, lacc, 0, 0, 0);
    }
    __syncthreads();
    buf ^= 1;
    t = tn;
    mbyte = mbyte2;
  }
#undef POP
#undef STAGE

  unsigned short* po = split ? op1b : op0b;
  for (int r = 0; r < 4; r++) {
    int q = qb64 * 64 + wave * 16 + quad * 4 + r;
    float inv = (lacc[r] > 0.f) ? 1.0f / lacc[r] : 0.0f;
    for (int d = 0; d < 8; d++)
      po[((size_t)h * S + q) * 128 + d * 16 + l16] = f2bf(oacc[d][r] * inv);
    if (l16 == 0)
      lp[((size_t)split * 12 + h) * S + q] = lacc[r];
  }
}

// ---------------- combine: o = (o0*l0 + o1*l1)/(l0+l1), gate by seq>=0 ----------
__global__ __launch_bounds__(256) void combine(const unsigned short* __restrict__ op0b,
                                               const unsigned short* __restrict__ op1b,
                                               const float* __restrict__ lp,
                                               const int* __restrict__ seq,
                                               unsigned short* __restrict__ ob, int S) {
  int e4 = blockIdx.x * 256 + threadIdx.x;   // ushort4 index
  int idx = e4 * 4;
  int per_h = S * 128;
  int h = idx / per_h;
  int rem = idx - h * per_h;
  int q = rem >> 7, dd = rem & 127;
  float l0 = lp[(size_t)h * S + q], l1 = lp[(size_t)(12 + h) * S + q];
  float tot = l0 + l1;
  float ok = (seq[q] >= 0 && tot > 0.f) ? 1.0f / tot : 0.0f;
  float w0 = l0 * ok, w1 = l1 * ok;
  ushort4 a = ((const ushort4*)op0b)[e4];
  ushort4 b = ((const ushort4*)op1b)[e4];
  ushort4 o;
  o.x = f2bf(bf2f(a.x) * w0 + bf2f(b.x) * w1);
  o.y = f2bf(bf2f(a.y) * w0 + bf2f(b.y) * w1);
  o.z = f2bf(bf2f(a.z) * w0 + bf2f(b.z) * w1);
  o.w = f2bf(bf2f(a.w) * w0 + bf2f(b.w) * w1);
  *(ushort4*)&ob[(size_t)q * 1536 + h * 128 + dd] = o;
}

extern "C" void kernel_launch(void* const* d_in, const int* in_sizes, int n_in,
                              void* d_out, int out_size, void* d_ws, size_t ws_size,
                              hipStream_t stream) {
  const float* x  = (const float*)d_in[0];
  const float* Wq = (const float*)d_in[1];
  const float* bq = (const float*)d_in[2];
  const float* Wk = (const float*)d_in[3];
  const float* bk = (const float*)d_in[4];
  const float* Wv = (const float*)d_in[5];
  const float* bv = (const float*)d_in[6];
  const float* gq = (const float*)d_in[7];
  const float* gk = (const float*)d_in[8];
  const float* Wo = (const float*)d_in[9];
  const float* bo = (const float*)d_in[10];
  const int* seq  = (const int*)d_in[11];
  const int* fr   = (const int*)d_in[12];
  const int* nz   = (const int*)d_in[13];
  const int* wsz  = (const int*)d_in[14];
  float* out = (float*)d_out;
  const int S = in_sizes[11];   // 3072
  const int D = 1536;

  char* ws = (char*)d_ws;
  size_t off = 0;
  unsigned short* x_bf = (unsigned short*)(ws + off); off += (size_t)S * D * 2;
  unsigned short* wt   = (unsigned short*)(ws + off); off += (size_t)4 * D * D * 2;
  unsigned short* qt   = (unsigned short*)(ws + off); off += (size_t)S * D * 2;
  unsigned short* ktb  = (unsigned short*)(ws + off); off += (size_t)S * D * 2;
  unsigned short* vtb  = (unsigned short*)(ws + off); off += (size_t)S * D * 2;
  unsigned short* o_bf = (unsigned short*)(ws + off); off += (size_t)S * D * 2;
  unsigned short* op0b = (unsigned short*)(ws + off); off += (size_t)S * D * 2;
  unsigned short* op1b = (unsigned short*)(ws + off); off += (size_t)S * D * 2;
  unsigned long long* tbm = (unsigned long long*)(ws + off); off += (size_t)(S / 16) * 16;
  unsigned char*  mbuf = (unsigned char*)(ws + off);  off += (size_t)(S / 16) * 96 * 64;
  float*          lp   = (float*)(ws + off);          off += (size_t)2 * 12 * S * 4;
  float*          ssq  = (float*)(ws + off);          off += (size_t)2 * 3072 * 4;

  dim3 blk(256);
  conv_f2bf<<<dim3((S * D / 4 + 255) / 256), blk, 0, stream>>>(x, x_bf, S * D / 4);
  prep_bitmap<<<dim3(1), blk, 0, stream>>>(seq, fr, nz, wsz, tbm, S);
  prep_mask<<<dim3(24, S / 16), blk, 0, stream>>>(seq, fr, nz, wsz, mbuf, S);
  conv_wt4<<<dim3(D / 64, D / 64, 4), blk, 0, stream>>>(Wq, Wk, Wv, Wo, wt);
  hipMemsetAsync(ssq, 0, (size_t)2 * 3072 * 4, stream);
  gemm_qkv<<<dim3(S / 128, 3 * D / 128), blk, 0, stream>>>(x_bf, wt, bq, bk, bv,
                                                           qt, ktb, vtb, ssq, S);
  rms_scale<<<dim3(S, 2), dim3(192), 0, stream>>>(qt, ktb, ssq, gq, gk);
  attn<<<dim3(D / 128, S / 64, 2), blk, 0, stream>>>(qt, ktb, vtb, mbuf, tbm,
                                                     op0b, op1b, lp, S);
  combine<<<dim3(12 * S * 128 / 4 / 256), blk, 0, stream>>>(op0b, op1b, lp, seq, o_bf, S);
  gemm_wo<<<dim3(S / 128, D / 64), blk, 0, stream>>>(o_bf, wt + (size_t)3 * D * D,
                                                     bo, out, S, D, D);
}

// Round 10
// 310.753 us; speedup vs baseline: 1.0469x; 1.0469x over previous
//
#include <hip/hip_runtime.h>
#include <hip/hip_bf16.h>
#include <stdint.h>

typedef __bf16 bf16x8 __attribute__((ext_vector_type(8)));
typedef float f32x4 __attribute__((ext_vector_type(4)));

__device__ __forceinline__ unsigned short f2bf(float f) {
  union { float f; unsigned int u; } v; v.f = f;
  unsigned int u = v.u;
  unsigned int r = (u + 0x7fffu + ((u >> 16) & 1u)) >> 16;
  return (unsigned short)r;
}
__device__ __forceinline__ float bf2f(unsigned short s) {
  union { unsigned int u; float f; } v; v.u = ((unsigned int)s) << 16; return v.f;
}

// ================= setup: x->bf16, W transposes, bitmaps, masks, ssq zero ============
// blocks [0,1152): conv x (4 float4/thread)
// blocks [1152,3456): W transpose tiles (4 matrices x 24x24)
// block 3456: packed-id tile bitmaps + per-qgroup live maps + zero ssq
// blocks [3457,3649): per-qgroup mask bytes
__global__ __launch_bounds__(256) void setup(
    const float* __restrict__ x,
    const float* __restrict__ Wq, const float* __restrict__ Wk,
    const float* __restrict__ Wv, const float* __restrict__ Wo,
    const int* __restrict__ seq, const int* __restrict__ fr,
    const int* __restrict__ nz, const int* __restrict__ wsz,
    unsigned short* __restrict__ x_bf, unsigned short* __restrict__ wt,
    unsigned long long* __restrict__ tbm, unsigned char* __restrict__ mb,
    float* __restrict__ ssq, int S) {
  __shared__ __align__(16) unsigned char smu[16384];
  int b = blockIdx.x, tid = threadIdx.x;
  if (b < 1152) {
    int base = b * 1024 + tid;
    for (int j = 0; j < 4; j++) {
      int i = base + j * 256;
      float4 v = ((const float4*)x)[i];
      ushort4 o;
      o.x = f2bf(v.x); o.y = f2bf(v.y); o.z = f2bf(v.z); o.w = f2bf(v.w);
      ((ushort4*)x_bf)[i] = o;
    }
  } else if (b < 3456) {
    int id = b - 1152;
    int z = id / 576, rem = id % 576;
    int kx = rem % 24, ny = rem / 24;
    const float* W = z == 0 ? Wq : (z == 1 ? Wk : (z == 2 ? Wv : Wo));
    unsigned short (*t)[65] = (unsigned short(*)[65])smu;
    int k0 = kx * 64, n0 = ny * 64;
    const int N = 1536, K = 1536;
    for (int i = 0; i < 16; i++) {
      int e = tid + i * 256;
      int r = e >> 6, c = e & 63;
      t[r][c] = f2bf(W[(size_t)(k0 + r) * N + n0 + c]);
    }
    __syncthreads();
    for (int i = 0; i < 16; i++) {
      int e = tid + i * 256;
      int r = e >> 6, c = e & 63;
      wt[(size_t)(z * 1536 + n0 + r) * K + k0 + c] = t[c][r];
    }
  } else if (b == 3456) {
    int* ks_ = (int*)smu;                       // 12 KB
    unsigned int* tm_ = (unsigned int*)(smu + 12288);
    int W = wsz[0];
    for (int i = tid; i < S; i += 256) {
      int sq = seq[i];
      ks_[i] = (sq < 0) ? 0 : ((1 << 9) | ((nz[i] & 1) << 8) | (fr[i] & 15) | (sq << 10));
    }
    for (int i = tid; i < 6144; i += 256) ssq[i] = 0.f;
    __syncthreads();
    for (int t = tid; t < S / 32; t += 256) {
      unsigned int m = 0;
      for (int j = 0; j < 32; j++) {
        int a = ks_[t * 32 + j];
        if (a & (1 << 9)) m |= (a & (1 << 8)) ? (1u << (16 + (a & 15))) : (1u << (a & 15));
      }
      tm_[t] = m;
    }
    __syncthreads();
    for (int qg = tid; qg < S / 16; qg += 256) {
      unsigned int allowed = 0;
      for (int j = 0; j < 16; j++) {
        int a = ks_[qg * 16 + j];
        if (!(a & (1 << 9))) continue;
        int fq = a & 15, nq = (a >> 8) & 1;
        int lo = fq - W; if (lo < 0) lo = 0;
        unsigned int lom = ~((1u << lo) - 1);
        if (nq) allowed |= (((1u << (fq + 1)) - 1) & lom) << 16;
        else    allowed |= ((((1u << fq) - 1) & lom) << 16) | (1u << fq);
      }
      unsigned long long b0 = 0, b1 = 0;
      for (int t = 0; t < 96; t++)
        if (tm_[t] & allowed) { if (t < 64) b0 |= 1ull << t; else b1 |= 1ull << (t - 64); }
      tbm[qg * 2] = b0; tbm[qg * 2 + 1] = b1;
    }
  } else {
    int qg = b - 3457;                          // 0..191
    int* ks_ = (int*)smu;
    int W = wsz[0];
    for (int i = tid; i < S; i += 256) {
      int sq = seq[i];
      ks_[i] = (sq < 0) ? 0 : ((1 << 9) | ((nz[i] & 1) << 8) | (fr[i] & 15) | (sq << 10));
    }
    __syncthreads();
    int wave = tid >> 6, lane = tid & 63, quad = lane >> 4, l16 = lane & 15;
    int aq[4];
    for (int r = 0; r < 4; r++) aq[r] = ks_[qg * 16 + quad * 4 + r];
    for (int t = wave; t < 96; t += 4) {
      int ak[2] = { ks_[t * 32 + l16], ks_[t * 32 + 16 + l16] };
      unsigned int byte = 0;
      for (int nt = 0; nt < 2; nt++) {
        int a = ak[nt];
        int kfr = a & 15, knz = (a >> 8) & 1, kvb = (a >> 9) & 1, ksq = a >> 10;
        for (int r = 0; r < 4; r++) {
          int bq_ = aq[r];
          int qfr = bq_ & 15, qnz = (bq_ >> 8) & 1, qvb = (bq_ >> 9) & 1, qsq = bq_ >> 10;
          bool ok  = qvb && kvb && (qsq == ksq);
          bool c2c = qnz && knz && (kfr <= qfr);
          bool n2c = !qnz && knz && (kfr < qfr);
          bool n2n = !qnz && !knz && (kfr == qfr);
          int df = qfr - kfr; df = df < 0 ? -df : df;
          if ((c2c || n2c || n2n) && ok && (df <= W)) byte |= 1u << (nt * 4 + r);
        }
      }
      mb[((size_t)qg * 96 + t) * 64 + lane] = (unsigned char)byte;
    }
  }
}

// ================= fused QKV GEMM ============
// region 0 -> qt bf16 [h][3072][128] RAW (no g, pre-norm) + ssq[0] atomics
// region 1 -> ktb bf16 [h][3072][128] = k * (gq*gk) per channel, pre-row-norm + ssq[1]
// region 2 -> vtb bf16 tile-blocked [h][96][128][32]
__global__ __launch_bounds__(256) void gemm_qkv(
    const unsigned short* __restrict__ A, const unsigned short* __restrict__ Bt,
    const float* __restrict__ bq, const float* __restrict__ bk, const float* __restrict__ bv,
    const float* __restrict__ gq, const float* __restrict__ gk,
    unsigned short* __restrict__ qt, unsigned short* __restrict__ ktb,
    unsigned short* __restrict__ vtb, float* __restrict__ ssq, int S) {
  const int K = 1536;
  __shared__ __align__(16) unsigned short smem[16384];   // As | Bs, reused as Cs
  unsigned short* As = smem;
  unsigned short* Bs = smem + 8192;
  unsigned short* Cs = smem;
  int tid = threadIdx.x, wave = tid >> 6, lane = tid & 63;
  int quad = lane >> 4, l16 = lane & 15;
  int m0 = blockIdx.x * 128, n0 = blockIdx.y * 128;
  int wm = (wave & 1) * 64, wn = (wave >> 1) * 64;
  int lr = lane >> 3, lc = (lane & 7) * 8;
  f32x4 acc[4][4] = {};
  for (int k0 = 0; k0 < K; k0 += 64) {
    for (int c = 0; c < 4; c++) {
      int chunk = wave * 4 + c;
      int row = chunk * 8 + lr;
      const unsigned short* ga = &A[(size_t)(m0 + row) * K + k0 + lc];
      const unsigned short* gb = &Bt[(size_t)(n0 + row) * K + k0 + lc];
      __builtin_amdgcn_global_load_lds(
          (const __attribute__((address_space(1))) unsigned int*)ga,
          (__attribute__((address_space(3))) unsigned int*)(As + chunk * 512), 16, 0, 0);
      __builtin_amdgcn_global_load_lds(
          (const __attribute__((address_space(1))) unsigned int*)gb,
          (__attribute__((address_space(3))) unsigned int*)(Bs + chunk * 512), 16, 0, 0);
    }
    __syncthreads();
    for (int kk = 0; kk < 64; kk += 32) {
      bf16x8 af[4], bfr[4];
      for (int i = 0; i < 4; i++)
        af[i] = *(const bf16x8*)&As[(wm + i * 16 + l16) * 64 + kk + quad * 8];
      for (int j = 0; j < 4; j++)
        bfr[j] = *(const bf16x8*)&Bs[(wn + j * 16 + l16) * 64 + kk + quad * 8];
      for (int i = 0; i < 4; i++)
        for (int j = 0; j < 4; j++)
          acc[i][j] = __builtin_amdgcn_mfma_f32_16x16x32_bf16(af[i], bfr[j], acc[i][j], 0, 0, 0);
    }
    __syncthreads();
  }
  int region = (n0 >= 3072) ? 2 : (n0 >= 1536 ? 1 : 0);
  int cbase = n0 - region * 1536;
  int hh = cbase >> 7;
  if (region < 2) {
    const float* bias = region == 0 ? bq : bk;
    float* ssqp = ssq + region * 3072;
    float ss[4][4] = {};
    for (int j = 0; j < 4; j++) {
      int col = cbase + wn + j * 16 + l16;
      float b = bias[col];
      float G = (region == 1) ? gq[col] * gk[col] : 1.0f;
      int cp = wn + j * 16 + l16;
      for (int i = 0; i < 4; i++)
        for (int r = 0; r < 4; r++) {
          float v = acc[i][j][r] + b;
          ss[i][r] += v * v;
          Cs[(wm + i * 16 + quad * 4 + r) * 128 + cp] = f2bf(v * G);
        }
    }
    for (int i = 0; i < 4; i++)
      for (int r = 0; r < 4; r++) {
        float v = ss[i][r];
        for (int o = 1; o < 16; o <<= 1) v += __shfl_xor(v, o);
        if (l16 == 0)
          atomicAdd(&ssqp[m0 + wm + i * 16 + quad * 4 + r], v);
      }
    __syncthreads();
    unsigned short* outp = (region == 0 ? qt : ktb) + (size_t)hh * 393216 + (size_t)m0 * 128;
    for (int p = 0; p < 8; p++) {
      int o = p * 2048 + tid * 8;
      *(uint4*)&outp[o] = *(const uint4*)&Cs[o];
    }
  } else {
    for (int j = 0; j < 4; j++) {
      int d = cbase + wn + j * 16 + l16;
      float b = bv[d];
      int cp = wn + j * 16 + l16;
      int c8 = l16 * 8;
      for (int i = 0; i < 4; i++)
        for (int r = 0; r < 4; r++) {
          int sp = wm + i * 16 + quad * 4 + r;
          Cs[cp * 128 + (sp ^ c8)] = f2bf(acc[i][j][r] + b);
        }
    }
    __syncthreads();
    unsigned short* outp = vtb + ((size_t)hh * 96 + (m0 >> 5)) * 4096;
    for (int p = 0; p < 8; p++) {
      int o = p * 2048 + tid * 8;
      int tile = o >> 12, rem = o & 4095;
      int dd = rem >> 5, s31 = rem & 31;
      int laddr = dd * 128 + ((tile * 32 + s31) ^ ((dd & 15) * 8));
      *(uint4*)&outp[o] = *(const uint4*)&Cs[laddr];
    }
  }
}

// ================= GEMM 128x64 (Wo): fp32 out + bias ============
__global__ __launch_bounds__(256) void gemm_wo(
    const unsigned short* __restrict__ A, const unsigned short* __restrict__ Bt,
    const float* __restrict__ bias, float* __restrict__ C, int M, int N, int K) {
  __shared__ __align__(16) unsigned short As[128 * 64];
  __shared__ __align__(16) unsigned short Bs[64 * 64];
  int tid = threadIdx.x, wave = tid >> 6, lane = tid & 63;
  int quad = lane >> 4, l16 = lane & 15;
  int m0 = blockIdx.x * 128, n0 = blockIdx.y * 64;
  int wm = (wave & 1) * 64, wn = (wave >> 1) * 32;
  int lr = lane >> 3, lc = (lane & 7) * 8;
  f32x4 acc[4][2] = {};
  for (int k0 = 0; k0 < K; k0 += 64) {
    for (int c = 0; c < 4; c++) {
      int chunk = wave * 4 + c;
      int row = chunk * 8 + lr;
      const unsigned short* ga = &A[(size_t)(m0 + row) * K + k0 + lc];
      __builtin_amdgcn_global_load_lds(
          (const __attribute__((address_space(1))) unsigned int*)ga,
          (__attribute__((address_space(3))) unsigned int*)(As + chunk * 512), 16, 0, 0);
    }
    for (int c = 0; c < 2; c++) {
      int chunk = wave * 2 + c;
      int row = chunk * 8 + lr;
      const unsigned short* gb = &Bt[(size_t)(n0 + row) * K + k0 + lc];
      __builtin_amdgcn_global_load_lds(
          (const __attribute__((address_space(1))) unsigned int*)gb,
          (__attribute__((address_space(3))) unsigned int*)(Bs + chunk * 512), 16, 0, 0);
    }
    __syncthreads();
    for (int kk = 0; kk < 64; kk += 32) {
      bf16x8 af[4], bfr[2];
      for (int i = 0; i < 4; i++)
        af[i] = *(const bf16x8*)&As[(wm + i * 16 + l16) * 64 + kk + quad * 8];
      for (int j = 0; j < 2; j++)
        bfr[j] = *(const bf16x8*)&Bs[(wn + j * 16 + l16) * 64 + kk + quad * 8];
      for (int i = 0; i < 4; i++)
        for (int j = 0; j < 2; j++)
          acc[i][j] = __builtin_amdgcn_mfma_f32_16x16x32_bf16(af[i], bfr[j], acc[i][j], 0, 0, 0);
    }
    __syncthreads();
  }
  for (int j = 0; j < 2; j++) {
    int col = n0 + wn + j * 16 + l16;
    float b = bias[col];
    for (int i = 0; i < 4; i++)
      for (int r = 0; r < 4; r++)
        C[(size_t)(m0 + wm + i * 16 + quad * 4 + r) * N + col] = acc[i][j][r] + b;
  }
}

// ================= flash attention: block = 64q x head x split ============
// s = sacc * qscale[row] * kscale[key] / sqrt(128); p = exp(s - 16); partials summable.
__global__ __launch_bounds__(256) void attn(
    const unsigned short* __restrict__ qt,   // [12][3072][128] raw
    const unsigned short* __restrict__ kt,   // [12][3072][128] k*(gq*gk)
    const unsigned short* __restrict__ vt,   // [12][96][128][32]
    const unsigned char* __restrict__ mb,    // [192][96][64]
    const unsigned long long* __restrict__ tbm, // [192][2]
    const float* __restrict__ ssq,           // [2][3072]
    unsigned short* __restrict__ op0b, unsigned short* __restrict__ op1b,
    float* __restrict__ lp, int S) {
  const int h = blockIdx.x;
  const int qb64 = blockIdx.y;
  const int split = blockIdx.z;
  int tid = threadIdx.x, wave = tid >> 6, lane = tid & 63;
  int quad = lane >> 4, l16 = lane & 15;
  const float scale = 0.088388347648318447f; // 1/sqrt(128)

  __shared__ __align__(16) unsigned short Ks[2][4096];
  __shared__ __align__(16) unsigned short Vs[2][4096];
  __shared__ __align__(16) unsigned short pshare[4][16][40];

  int qg = qb64 * 4 + wave;
  unsigned long long bm0 = tbm[(qb64 * 4) * 2]     | tbm[(qb64 * 4 + 1) * 2] |
                           tbm[(qb64 * 4 + 2) * 2] | tbm[(qb64 * 4 + 3) * 2];
  unsigned long long bm1 = tbm[(qb64 * 4) * 2 + 1]     | tbm[(qb64 * 4 + 1) * 2 + 1] |
                           tbm[(qb64 * 4 + 2) * 2 + 1] | tbm[(qb64 * 4 + 3) * 2 + 1];
  unsigned long long wb0 = tbm[qg * 2], wb1 = tbm[qg * 2 + 1];

  const unsigned short* kth = kt + (size_t)h * 96 * 4096;
  const unsigned short* vth = vt + (size_t)h * 96 * 4096;
  const unsigned char* mbq = mb + (size_t)qg * 96 * 64;

  bf16x8 qf[4];
  {
    const unsigned short* qp = qt + ((size_t)(h * 192 + qg) * 16 + l16) * 128 + quad * 8;
    for (int ks = 0; ks < 4; ks++) qf[ks] = *(const bf16x8*)&qp[ks * 32];
  }
  // row scales (scale folded in)
  float qs[4];
  for (int r = 0; r < 4; r++) {
    int row = qb64 * 64 + wave * 16 + quad * 4 + r;
    qs[r] = rsqrtf(ssq[row] * (1.0f / 1536.0f) + 1e-5f) * scale;
  }
  const float* ssk = ssq + 3072;

  f32x4 oacc[8] = {};
  f32x4 lacc = {};
  const __bf16 onebf = (__bf16)1.0f;
  const bf16x8 ones = {onebf, onebf, onebf, onebf, onebf, onebf, onebf, onebf};

#define POP(dst) do { \
    if (bm0) { dst = __builtin_ctzll(bm0); bm0 &= bm0 - 1; } \
    else if (bm1) { dst = 64 + __builtin_ctzll(bm1); bm1 &= bm1 - 1; } \
    else dst = -1; } while (0)

#define STAGE(t_, b_) do { \
    for (int j = 0; j < 2; j++) { \
      int slot = j * 256 + tid; \
      int key = slot >> 4, cc = slot & 15; \
      const unsigned short* src = kth + (size_t)(t_) * 4096 + key * 128 + (cc ^ (key & 15)) * 8; \
      __builtin_amdgcn_global_load_lds( \
          (const __attribute__((address_space(1))) unsigned int*)src, \
          (__attribute__((address_space(3))) unsigned int*)(&Ks[b_][0] + j * 2048 + wave * 512), \
          16, 0, 0); \
    } \
    for (int j = 0; j < 2; j++) { \
      int slot = j * 256 + tid; \
      int row = slot >> 2, cc = slot & 3; \
      const unsigned short* src = vth + (size_t)(t_) * 4096 + row * 32 + (cc ^ ((row >> 1) & 3)) * 8; \
      __builtin_amdgcn_global_load_lds( \
          (const __attribute__((address_space(1))) unsigned int*)src, \
          (__attribute__((address_space(3))) unsigned int*)(&Vs[b_][0] + j * 2048 + wave * 512), \
          16, 0, 0); \
    } } while (0)

  int t, dsc;
  if (split) POP(dsc);
  POP(t);
  unsigned int mbyte = 0;
  float kss0 = 0.f, kss1 = 0.f;
  if (t >= 0) {
    STAGE(t, 0);
    mbyte = mbq[t * 64 + lane];
    kss0 = ssk[t * 32 + l16]; kss1 = ssk[t * 32 + 16 + l16];
  }
  __syncthreads();
  int buf = 0;

  while (t >= 0) {
    POP(dsc);
    int tn; POP(tn);
    unsigned int mbyte2 = 0;
    float nss0 = 0.f, nss1 = 0.f;
    if (tn >= 0) {
      STAGE(tn, buf ^ 1);
      mbyte2 = mbq[tn * 64 + lane];
      nss0 = ssk[tn * 32 + l16]; nss1 = ssk[tn * 32 + 16 + l16];
    }

    bool live = (t < 64) ? ((wb0 >> t) & 1) : ((wb1 >> (t - 64)) & 1);
    if (live) {
      f32x4 sacc[2] = {};
      for (int nt = 0; nt < 2; nt++) {
        int key = nt * 16 + l16;
        for (int ks = 0; ks < 4; ks++) {
          int cc = (ks * 4 + quad) ^ l16;
          bf16x8 kf = *(const bf16x8*)&Ks[buf][(key * 16 + cc) * 8];
          sacc[nt] = __builtin_amdgcn_mfma_f32_16x16x32_bf16(qf[ks], kf, sacc[nt], 0, 0, 0);
        }
      }
      float ksc[2];
      ksc[0] = rsqrtf(kss0 * (1.0f / 1536.0f) + 1e-5f);
      ksc[1] = rsqrtf(kss1 * (1.0f / 1536.0f) + 1e-5f);
      for (int nt = 0; nt < 2; nt++)
        for (int r = 0; r < 4; r++) {
          float e = __expf(sacc[nt][r] * (qs[r] * ksc[nt]) - 16.0f);
          float p = ((mbyte >> (nt * 4 + r)) & 1) ? e : 0.0f;
          pshare[wave][quad * 4 + r][nt * 16 + l16] = f2bf(p);
        }
      __asm__ __volatile__("s_waitcnt lgkmcnt(0)" ::: "memory");
      bf16x8 pf = *(const bf16x8*)&pshare[wave][l16][quad * 8];
      for (int d = 0; d < 8; d++) {
        int row = d * 16 + l16;
        int cc = quad ^ ((l16 >> 1) & 3);
        bf16x8 vf = *(const bf16x8*)&Vs[buf][(row * 4 + cc) * 8];
        oacc[d] = __builtin_amdgcn_mfma_f32_16x16x32_bf16(pf, vf, oacc[d], 0, 0, 0);
      }
      lacc = __builtin_amdgcn_mfma_f32_16x16x32_bf16(pf, ones, lacc, 0, 0, 0);
    }
    __syncthreads();
    buf ^= 1;
    t = tn;
    mbyte = mbyte2;
    kss0 = nss0; kss1 = nss1;
  }
#undef POP
#undef STAGE

  unsigned short* po = split ? op1b : op0b;
  for (int r = 0; r < 4; r++) {
    int q = qb64 * 64 + wave * 16 + quad * 4 + r;
    float inv = (lacc[r] > 0.f) ? 1.0f / lacc[r] : 0.0f;
    for (int d = 0; d < 8; d++)
      po[((size_t)h * S + q) * 128 + d * 16 + l16] = f2bf(oacc[d][r] * inv);
    if (l16 == 0)
      lp[((size_t)split * 12 + h) * S + q] = lacc[r];
  }
}

// ================= combine: o = (o0*l0 + o1*l1)/(l0+l1), gate by seq>=0 ============
__global__ __launch_bounds__(256) void combine(const unsigned short* __restrict__ op0b,
                                               const unsigned short* __restrict__ op1b,
                                               const float* __restrict__ lp,
                                               const int* __restrict__ seq,
                                               unsigned short* __restrict__ ob, int S) {
  int e4 = blockIdx.x * 256 + threadIdx.x;
  int idx = e4 * 4;
  int per_h = S * 128;
  int h = idx / per_h;
  int rem = idx - h * per_h;
  int q = rem >> 7, dd = rem & 127;
  float l0 = lp[(size_t)h * S + q], l1 = lp[(size_t)(12 + h) * S + q];
  float tot = l0 + l1;
  float ok = (seq[q] >= 0 && tot > 0.f) ? 1.0f / tot : 0.0f;
  float w0 = l0 * ok, w1 = l1 * ok;
  ushort4 a = ((const ushort4*)op0b)[e4];
  ushort4 b = ((const ushort4*)op1b)[e4];
  ushort4 o;
  o.x = f2bf(bf2f(a.x) * w0 + bf2f(b.x) * w1);
  o.y = f2bf(bf2f(a.y) * w0 + bf2f(b.y) * w1);
  o.z = f2bf(bf2f(a.z) * w0 + bf2f(b.z) * w1);
  o.w = f2bf(bf2f(a.w) * w0 + bf2f(b.w) * w1);
  *(ushort4*)&ob[(size_t)q * 1536 + h * 128 + dd] = o;
}

extern "C" void kernel_launch(void* const* d_in, const int* in_sizes, int n_in,
                              void* d_out, int out_size, void* d_ws, size_t ws_size,
                              hipStream_t stream) {
  const float* x  = (const float*)d_in[0];
  const float* Wq = (const float*)d_in[1];
  const float* bq = (const float*)d_in[2];
  const float* Wk = (const float*)d_in[3];
  const float* bk = (const float*)d_in[4];
  const float* Wv = (const float*)d_in[5];
  const float* bv = (const float*)d_in[6];
  const float* gq = (const float*)d_in[7];
  const float* gk = (const float*)d_in[8];
  const float* Wo = (const float*)d_in[9];
  const float* bo = (const float*)d_in[10];
  const int* seq  = (const int*)d_in[11];
  const int* fr   = (const int*)d_in[12];
  const int* nz   = (const int*)d_in[13];
  const int* wsz  = (const int*)d_in[14];
  float* out = (float*)d_out;
  const int S = in_sizes[11];   // 3072
  const int D = 1536;

  char* ws = (char*)d_ws;
  size_t off = 0;
  unsigned short* x_bf = (unsigned short*)(ws + off); off += (size_t)S * D * 2;
  unsigned short* wt   = (unsigned short*)(ws + off); off += (size_t)4 * D * D * 2;
  unsigned short* qt   = (unsigned short*)(ws + off); off += (size_t)S * D * 2;
  unsigned short* ktb  = (unsigned short*)(ws + off); off += (size_t)S * D * 2;
  unsigned short* vtb  = (unsigned short*)(ws + off); off += (size_t)S * D * 2;
  unsigned short* o_bf = (unsigned short*)(ws + off); off += (size_t)S * D * 2;
  unsigned short* op0b = (unsigned short*)(ws + off); off += (size_t)S * D * 2;
  unsigned short* op1b = (unsigned short*)(ws + off); off += (size_t)S * D * 2;
  unsigned long long* tbm = (unsigned long long*)(ws + off); off += (size_t)(S / 16) * 16;
  unsigned char*  mbuf = (unsigned char*)(ws + off);  off += (size_t)(S / 16) * 96 * 64;
  float*          lp   = (float*)(ws + off);          off += (size_t)2 * 12 * S * 4;
  float*          ssq  = (float*)(ws + off);          off += (size_t)2 * 3072 * 4;

  dim3 blk(256);
  setup<<<dim3(3649), blk, 0, stream>>>(x, Wq, Wk, Wv, Wo, seq, fr, nz, wsz,
                                        x_bf, wt, tbm, mbuf, ssq, S);
  gemm_qkv<<<dim3(S / 128, 3 * D / 128), blk, 0, stream>>>(x_bf, wt, bq, bk, bv, gq, gk,
                                                           qt, ktb, vtb, ssq, S);
  attn<<<dim3(D / 128, S / 64, 2), blk, 0, stream>>>(qt, ktb, vtb, mbuf, tbm, ssq,
                                                     op0b, op1b, lp, S);
  combine<<<dim3(12 * S * 128 / 4 / 256), blk, 0, stream>>>(op0b, op1b, lp, seq, o_bf, S);
  gemm_wo<<<dim3(S / 128, D / 64), blk, 0, stream>>>(o_bf, wt + (size_t)3 * D * D,
                                                     bo, out, S, D, D);
}